// Round 1
// baseline (1221.957 us; speedup 1.0000x reference)
//
#include <hip/hip_runtime.h>
#include <hip/hip_bf16.h>
#include <stdint.h>

#define HIDDEN 1024
#define OUTD   512
#define NSEQ   8192
#define MTOT   16384  // 2*NSEQ

typedef unsigned short u16;
typedef __attribute__((ext_vector_type(8))) short short8;  // 8 bf16 (4 VGPRs)
typedef __attribute__((ext_vector_type(4))) float f32x4;

__device__ __forceinline__ u16 f2b(float f){
  union { __hip_bfloat16 h; u16 u; } c; c.h = __float2bfloat16(f); return c.u;
}

__device__ __forceinline__ void gload_lds16(const void* g, void* l){
  __builtin_amdgcn_global_load_lds(
    (const __attribute__((address_space(1))) uint32_t*)(uintptr_t)g,
    (__attribute__((address_space(3))) uint32_t*)(uintptr_t)l, 16, 0, 0);
}

#define MFMA16(a,b,c) __builtin_amdgcn_mfma_f32_16x16x32_bf16((a),(b),(c),0,0,0)

// ---------------- f32 -> bf16 convert ----------------
__global__ void cvt_bf16_kernel(const float* __restrict__ in, u16* __restrict__ out, int n4){
  int i = blockIdx.x*blockDim.x + threadIdx.x;
  int stride = gridDim.x*blockDim.x;
  for (; i < n4; i += stride){
    float4 v = ((const float4*)in)[i];
    ushort4 o;
    o.x = f2b(v.x); o.y = f2b(v.y); o.z = f2b(v.z); o.w = f2b(v.w);
    ((ushort4*)out)[i] = o;
  }
}

// ---------------- transpose f32[R][C] -> bf16[C][R] ----------------
__global__ void transpose_bf16_kernel(const float* __restrict__ in, u16* __restrict__ out, int R, int C){
  __shared__ float t[32][33];
  int tx = threadIdx.x, ty = threadIdx.y;
  int c0 = blockIdx.x*32, r0 = blockIdx.y*32;
  #pragma unroll
  for (int i = ty; i < 32; i += 8) t[i][tx] = in[(size_t)(r0+i)*C + c0 + tx];
  __syncthreads();
  #pragma unroll
  for (int i = ty; i < 32; i += 8) out[(size_t)(c0+i)*R + r0 + tx] = f2b(t[tx][i]);
}

// ---------------- GEMM: C[M,N] = A[M,K] @ BT[N,K]^T (+bias, opt ELU, *scale), bf16 out ----
// m97 structure: 128x128 tile, BK=32, 4 waves, 4x4 16x16x32 frags/wave, global_load_lds w=16
template<bool ELU_ACT, bool BIAS_ROW>
__global__ __launch_bounds__(256, 2) void gemm_bt(
    const u16* __restrict__ A, const u16* __restrict__ BT,
    const float* __restrict__ bias, u16* __restrict__ C,
    int M, int N, int K, float outscale)
{
  __shared__ u16 As[128*32];
  __shared__ u16 Bs[128*32];
  const int tid = threadIdx.x;
  const int w = tid >> 6, l = tid & 63;
  const int lr = l & 15, lg = l >> 4;
  const int brow = blockIdx.y * 128, bcol = blockIdx.x * 128;
  const int wr = w >> 1, wc = w & 1;
  f32x4 acc[4][4];
  #pragma unroll
  for (int i=0;i<4;i++)
    #pragma unroll
    for (int j=0;j<4;j++) acc[i][j] = f32x4{0.f,0.f,0.f,0.f};

  for (int k0 = 0; k0 < K; k0 += 32){
    __syncthreads();
    {
      int sb = w*64;
      int s0 = sb + l;
      int s1 = 256 + sb + l;
      gload_lds16(A  + (size_t)(brow + (s0>>2))*K + k0 + (s0&3)*8, As + sb*8);
      gload_lds16(A  + (size_t)(brow + (s1>>2))*K + k0 + (s1&3)*8, As + (256+sb)*8);
      gload_lds16(BT + (size_t)(bcol + (s0>>2))*K + k0 + (s0&3)*8, Bs + sb*8);
      gload_lds16(BT + (size_t)(bcol + (s1>>2))*K + k0 + (s1&3)*8, Bs + (256+sb)*8);
    }
    __syncthreads();
    short8 a[4], b[4];
    #pragma unroll
    for (int i=0;i<4;i++){
      a[i] = *(const short8*)(As + (wr*64 + i*16 + lr)*32 + lg*8);
      b[i] = *(const short8*)(Bs + (wc*64 + i*16 + lr)*32 + lg*8);
    }
    #pragma unroll
    for (int i=0;i<4;i++)
      #pragma unroll
      for (int j=0;j<4;j++)
        acc[i][j] = MFMA16(a[i], b[j], acc[i][j]);
  }

  // C/D layout (m89-verified): col = lane&15, row = (lane>>4)*4 + reg
  #pragma unroll
  for (int i=0;i<4;i++)
    #pragma unroll
    for (int j=0;j<4;j++){
      int col = bcol + wc*64 + j*16 + lr;
      float bc = BIAS_ROW ? 0.f : bias[col];
      #pragma unroll
      for (int r=0;r<4;r++){
        int row = brow + wr*64 + i*16 + lg*4 + r;
        float v = acc[i][j][r] + (BIAS_ROW ? bias[row] : bc);
        if (ELU_ACT) v = v > 0.f ? v : expm1f(v);
        v *= outscale;
        C[(size_t)row*N + col] = f2b(v);
      }
    }
}

// ---------------- flash attention ----------------
// grid = 256: dir = bx>>7, qblock(64 rows) = bx&127. 4 waves, 16 q-rows/wave.
// Qb pre-scaled by 1/16. Kb [16384,512] bf16. Vt [512,16384] bf16 (V transposed).
// out f32 [8192, 1024], dir d writes cols [d*512, d*512+512).
__global__ __launch_bounds__(256, 1) void flash_attn(
    const u16* __restrict__ Qb, const u16* __restrict__ Kb,
    const u16* __restrict__ Vt, float* __restrict__ out)
{
  __shared__ u16 Ks[32*512];    // K tile  [kv=32][d=512], 16B-slot XOR-swizzled by (row&7)
  __shared__ u16 Vts[512*32];   // Vt tile [d=512][kv=32], slot swizzled by (d^(d>>2))&3
  __shared__ u16 Plds[4][16*32];// per-wave P, slot swizzled by (q^(q>>2))&3
  const int tid = threadIdx.x;
  const int w = tid >> 6, l = tid & 63;
  const int lr = l & 15, lg = l >> 4;
  const int dir = blockIdx.x >> 7;
  const int qb  = blockIdx.x & 127;
  const int qrow0 = dir*NSEQ + qb*64 + w*16;
  const int kvbase = (1-dir)*NSEQ;

  // Q fragments in registers: rows qrow0+lr, k = kt*32 + lg*8
  short8 qf[16];
  #pragma unroll
  for (int kt=0; kt<16; kt++)
    qf[kt] = *(const short8*)(Qb + (size_t)(qrow0 + lr)*OUTD + kt*32 + lg*8);

  f32x4 o[32];
  #pragma unroll
  for (int i=0;i<32;i++) o[i] = f32x4{0.f,0.f,0.f,0.f};
  float m[4]  = {-1e30f,-1e30f,-1e30f,-1e30f};
  float ls[4] = {0.f,0.f,0.f,0.f};

  u16* Pw = &Plds[w][0];
  const int fq = (lr ^ (lr>>2)) & 3;

  for (int t=0; t<NSEQ/32; t++){
    __syncthreads();   // previous tile fully consumed
    // stage K tile: 2048 x 16B segs; linear LDS dest, inverse-swizzled source
    #pragma unroll
    for (int i=0;i<8;i++){
      int sb = i*256 + w*64;
      int s = sb + l;
      int r = s >> 6;     // kv row 0..31
      int p = s & 63;     // 16B slot in row
      gload_lds16(Kb + (size_t)(kvbase + t*32 + r)*OUTD + ((p ^ (r&7))*8), Ks + sb*8);
    }
    // stage Vt tile
    #pragma unroll
    for (int i=0;i<8;i++){
      int sb = i*256 + w*64;
      int s = sb + l;
      int d = s >> 2;     // d row 0..511
      int p = s & 3;      // 16B slot in row
      int fd = (d ^ (d>>2)) & 3;
      gload_lds16(Vt + (size_t)d*MTOT + kvbase + t*32 + ((p ^ fd)*8), Vts + sb*8);
    }
    __syncthreads();   // compiler drains vmcnt before barrier

    // S = Q @ K^T  (A=Q rows, B=K rows; swizzled reads)
    f32x4 s0 = f32x4{0.f,0.f,0.f,0.f}, s1 = s0;
    #pragma unroll
    for (int kt=0; kt<16; kt++){
      short8 b0 = *(const short8*)(Ks + (size_t)(lr)*512    + (((kt*4+lg) ^ (lr&7))*8));
      short8 b1 = *(const short8*)(Ks + (size_t)(16+lr)*512 + (((kt*4+lg) ^ (lr&7))*8));
      s0 = MFMA16(qf[kt], b0, s0);
      s1 = MFMA16(qf[kt], b1, s1);
    }

    // online softmax: row = lg*4+j, col = nj*16+lr; reduce over low-4 lane bits
    float corr[4];
    #pragma unroll
    for (int j=0;j<4;j++){
      float mx = fmaxf(s0[j], s1[j]);
      mx = fmaxf(mx, __shfl_xor(mx, 1));
      mx = fmaxf(mx, __shfl_xor(mx, 2));
      mx = fmaxf(mx, __shfl_xor(mx, 4));
      mx = fmaxf(mx, __shfl_xor(mx, 8));
      float mn = fmaxf(m[j], mx);
      corr[j] = exp2f((m[j] - mn)*1.44269504f);
      float p0 = exp2f((s0[j] - mn)*1.44269504f);
      float p1 = exp2f((s1[j] - mn)*1.44269504f);
      m[j] = mn;
      s0[j] = p0; s1[j] = p1;
      float sm = p0 + p1;
      sm += __shfl_xor(sm, 1);
      sm += __shfl_xor(sm, 2);
      sm += __shfl_xor(sm, 4);
      sm += __shfl_xor(sm, 8);
      ls[j] = ls[j]*corr[j] + sm;
    }

    // P (C-layout) -> per-wave LDS as bf16 (A-layout source for PV)
    #pragma unroll
    for (int j=0;j<4;j++){
      int q = lg*4 + j;
      int fqw = (q ^ (q>>2)) & 3;
      int ps0 = (lr>>3) ^ fqw;            // col = lr
      int ps1 = ((16+lr)>>3) ^ fqw;       // col = 16+lr
      Pw[q*32 + ps0*8 + (lr&7)] = f2b(s0[j]);
      Pw[q*32 + ps1*8 + (lr&7)] = f2b(s1[j]);
    }
    // rescale O
    #pragma unroll
    for (int i=0;i<32;i++){
      o[i][0] *= corr[0]; o[i][1] *= corr[1]; o[i][2] *= corr[2]; o[i][3] *= corr[3];
    }
    // PV: O[16,512] += P[16,32] @ V[32,512]  (B from Vts rows = d)
    short8 pa = *(const short8*)(Pw + lr*32 + ((lg ^ fq)*8));
    #pragma unroll
    for (int nj=0; nj<32; nj++){
      int d = nj*16 + lr;
      int fd = (d ^ (d>>2)) & 3;
      short8 bv = *(const short8*)(Vts + d*32 + ((lg ^ fd)*8));
      o[nj] = MFMA16(pa, bv, o[nj]);
    }
  }

  float inv[4];
  #pragma unroll
  for (int j=0;j<4;j++) inv[j] = 1.f / ls[j];
  #pragma unroll
  for (int nj=0; nj<32; nj++){
    int col = dir*OUTD + nj*16 + lr;
    #pragma unroll
    for (int j=0;j<4;j++){
      int row = qb*64 + w*16 + lg*4 + j;
      out[(size_t)row*(2*OUTD) + col] = o[nj][j]*inv[j];
    }
  }
}

// ---------------- workspace layout ----------------
#define OFF_W1T  ((size_t)0)                          // 1024*1024*2
#define OFF_W2T  (OFF_W1T + (size_t)1024*1024*2)      // 512*1024*2
#define OFF_WQT  (OFF_W2T + (size_t)512*1024*2)       // 512*512*2
#define OFF_WKT  (OFF_WQT + (size_t)512*512*2)
#define OFF_WVT  (OFF_WKT + (size_t)512*512*2)
#define OFF_XC   (OFF_WVT + (size_t)512*512*2)        // 16384*1024*2 (later: Qb,Kb)
#define OFF_H    (OFF_XC  + (size_t)MTOT*HIDDEN*2)    // 16384*1024*2 (later: Vt)
#define OFF_P    (OFF_H   + (size_t)MTOT*HIDDEN*2)    // 16384*512*2
#define OFF_QB   OFF_XC
#define OFF_KB   (OFF_XC + (size_t)MTOT*OUTD*2)
#define OFF_VT   OFF_H

extern "C" void kernel_launch(void* const* d_in, const int* in_sizes, int n_in,
                              void* d_out, int out_size, void* d_ws, size_t ws_size,
                              hipStream_t stream) {
  const float* za = (const float*)d_in[0];
  const float* zb = (const float*)d_in[1];
  const float* W1 = (const float*)d_in[2];
  const float* b1 = (const float*)d_in[3];
  const float* W2 = (const float*)d_in[4];
  const float* b2 = (const float*)d_in[5];
  const float* Wq = (const float*)d_in[6];
  const float* bq = (const float*)d_in[7];
  const float* Wk = (const float*)d_in[8];
  const float* bk = (const float*)d_in[9];
  const float* Wv = (const float*)d_in[10];
  const float* bv = (const float*)d_in[11];
  float* out = (float*)d_out;
  char* ws = (char*)d_ws;

  u16* W1T = (u16*)(ws + OFF_W1T);
  u16* W2T = (u16*)(ws + OFF_W2T);
  u16* WqT = (u16*)(ws + OFF_WQT);
  u16* WkT = (u16*)(ws + OFF_WKT);
  u16* WvT = (u16*)(ws + OFF_WVT);
  u16* Xc  = (u16*)(ws + OFF_XC);
  u16* H   = (u16*)(ws + OFF_H);
  u16* P   = (u16*)(ws + OFF_P);
  u16* Qb  = (u16*)(ws + OFF_QB);
  u16* Kb  = (u16*)(ws + OFF_KB);
  u16* Vt  = (u16*)(ws + OFF_VT);

  // inputs -> bf16 (za | zb stacked)
  cvt_bf16_kernel<<<2048, 256, 0, stream>>>(za, Xc, NSEQ*HIDDEN/4);
  cvt_bf16_kernel<<<2048, 256, 0, stream>>>(zb, Xc + (size_t)NSEQ*HIDDEN, NSEQ*HIDDEN/4);
  // weight transposes (f32 -> bf16)
  transpose_bf16_kernel<<<dim3(32,32), dim3(32,8), 0, stream>>>(W1, W1T, 1024, 1024);
  transpose_bf16_kernel<<<dim3(16,32), dim3(32,8), 0, stream>>>(W2, W2T, 1024, 512);
  transpose_bf16_kernel<<<dim3(16,16), dim3(32,8), 0, stream>>>(Wq, WqT, 512, 512);
  transpose_bf16_kernel<<<dim3(16,16), dim3(32,8), 0, stream>>>(Wk, WkT, 512, 512);
  transpose_bf16_kernel<<<dim3(16,16), dim3(32,8), 0, stream>>>(Wv, WvT, 512, 512);

  // H = ELU(Xc @ W1 + b1)    [16384,1024]
  gemm_bt<true,false><<<dim3(HIDDEN/128, MTOT/128), 256, 0, stream>>>(
      Xc, W1T, b1, H, MTOT, HIDDEN, HIDDEN, 1.f);
  // P = H @ W2 + b2          [16384,512]
  gemm_bt<false,false><<<dim3(OUTD/128, MTOT/128), 256, 0, stream>>>(
      H, W2T, b2, P, MTOT, OUTD, HIDDEN, 1.f);
  // Qb = (P @ Wq + bq)/16    [16384,512]   (scale folded in)
  gemm_bt<false,false><<<dim3(OUTD/128, MTOT/128), 256, 0, stream>>>(
      P, WqT, bq, Qb, MTOT, OUTD, OUTD, 0.0625f);
  // Kb = P @ Wk + bk         [16384,512]
  gemm_bt<false,false><<<dim3(OUTD/128, MTOT/128), 256, 0, stream>>>(
      P, WkT, bk, Kb, MTOT, OUTD, OUTD, 1.f);
  // Vt = (P @ Wv + bv)^T as GEMM: Vt[d,j] = sum_k WvT[d,k]*P[j,k] + bv[d]   [512,16384]
  gemm_bt<false,true><<<dim3(MTOT/128, OUTD/128), 256, 0, stream>>>(
      WvT, P, bv, Vt, OUTD, MTOT, OUTD, 1.f);

  // flash attention, both directions
  flash_attn<<<256, 256, 0, stream>>>(Qb, Kb, Vt, out);
}

// Round 2
// 1149.769 us; speedup vs baseline: 1.0628x; 1.0628x over previous
//
#include <hip/hip_runtime.h>
#include <hip/hip_bf16.h>
#include <stdint.h>

#define HIDDEN 1024
#define OUTD   512
#define NSEQ   8192
#define MTOT   16384  // 2*NSEQ

typedef unsigned short u16;
typedef __attribute__((ext_vector_type(8))) short short8;  // 8 bf16 (4 VGPRs)
typedef __attribute__((ext_vector_type(4))) float f32x4;

__device__ __forceinline__ u16 f2b(float f){
  union { __hip_bfloat16 h; u16 u; } c; c.h = __float2bfloat16(f); return c.u;
}

__device__ __forceinline__ void gload_lds16(const void* g, void* l){
  __builtin_amdgcn_global_load_lds(
    (const __attribute__((address_space(1))) uint32_t*)(uintptr_t)g,
    (__attribute__((address_space(3))) uint32_t*)(uintptr_t)l, 16, 0, 0);
}

#define MFMA16(a,b,c) __builtin_amdgcn_mfma_f32_16x16x32_bf16((a),(b),(c),0,0,0)

// ---------------- f32 -> bf16 convert ----------------
__global__ void cvt_bf16_kernel(const float* __restrict__ in, u16* __restrict__ out, int n4){
  int i = blockIdx.x*blockDim.x + threadIdx.x;
  int stride = gridDim.x*blockDim.x;
  for (; i < n4; i += stride){
    float4 v = ((const float4*)in)[i];
    ushort4 o;
    o.x = f2b(v.x); o.y = f2b(v.y); o.z = f2b(v.z); o.w = f2b(v.w);
    ((ushort4*)out)[i] = o;
  }
}

// ---------------- transpose f32[R][C] -> bf16[C][R] ----------------
__global__ void transpose_bf16_kernel(const float* __restrict__ in, u16* __restrict__ out, int R, int C){
  __shared__ float t[32][33];
  int tx = threadIdx.x, ty = threadIdx.y;
  int c0 = blockIdx.x*32, r0 = blockIdx.y*32;
  #pragma unroll
  for (int i = ty; i < 32; i += 8) t[i][tx] = in[(size_t)(r0+i)*C + c0 + tx];
  __syncthreads();
  #pragma unroll
  for (int i = ty; i < 32; i += 8) out[(size_t)(c0+i)*R + r0 + tx] = f2b(t[tx][i]);
}

// ---------------- GEMM: C[M,N] = A[M,K] @ BT[N,K]^T (+bias, opt ELU, *scale), bf16 out ----
template<bool ELU_ACT, bool BIAS_ROW>
__global__ __launch_bounds__(256, 2) void gemm_bt(
    const u16* __restrict__ A, const u16* __restrict__ BT,
    const float* __restrict__ bias, u16* __restrict__ C,
    int M, int N, int K, float outscale)
{
  __shared__ u16 As[128*32];
  __shared__ u16 Bs[128*32];
  const int tid = threadIdx.x;
  const int w = tid >> 6, l = tid & 63;
  const int lr = l & 15, lg = l >> 4;
  const int brow = blockIdx.y * 128, bcol = blockIdx.x * 128;
  const int wr = w >> 1, wc = w & 1;
  f32x4 acc[4][4];
  #pragma unroll
  for (int i=0;i<4;i++)
    #pragma unroll
    for (int j=0;j<4;j++) acc[i][j] = f32x4{0.f,0.f,0.f,0.f};

  for (int k0 = 0; k0 < K; k0 += 32){
    __syncthreads();
    {
      int sb = w*64;
      int s0 = sb + l;
      int s1 = 256 + sb + l;
      gload_lds16(A  + (size_t)(brow + (s0>>2))*K + k0 + (s0&3)*8, As + sb*8);
      gload_lds16(A  + (size_t)(brow + (s1>>2))*K + k0 + (s1&3)*8, As + (256+sb)*8);
      gload_lds16(BT + (size_t)(bcol + (s0>>2))*K + k0 + (s0&3)*8, Bs + sb*8);
      gload_lds16(BT + (size_t)(bcol + (s1>>2))*K + k0 + (s1&3)*8, Bs + (256+sb)*8);
    }
    __syncthreads();
    short8 a[4], b[4];
    #pragma unroll
    for (int i=0;i<4;i++){
      a[i] = *(const short8*)(As + (wr*64 + i*16 + lr)*32 + lg*8);
      b[i] = *(const short8*)(Bs + (wc*64 + i*16 + lr)*32 + lg*8);
    }
    #pragma unroll
    for (int i=0;i<4;i++)
      #pragma unroll
      for (int j=0;j<4;j++)
        acc[i][j] = MFMA16(a[i], b[j], acc[i][j]);
  }

  // C/D layout (m89-verified): col = lane&15, row = (lane>>4)*4 + reg
  #pragma unroll
  for (int i=0;i<4;i++)
    #pragma unroll
    for (int j=0;j<4;j++){
      int col = bcol + wc*64 + j*16 + lr;
      float bc = BIAS_ROW ? 0.f : bias[col];
      #pragma unroll
      for (int r=0;r<4;r++){
        int row = brow + wr*64 + i*16 + lg*4 + r;
        float v = acc[i][j][r] + (BIAS_ROW ? bias[row] : bc);
        if (ELU_ACT) v = v > 0.f ? v : expm1f(v);
        v *= outscale;
        C[(size_t)row*N + col] = f2b(v);
      }
    }
}

// ---------------- flash attention (v2: double-buffered, defer-max, setprio, XCD map) ----
// grid = 256. XCD-bijective: xcd = bx&7 owns 32 q-blocks of ONE direction so all
// CUs on an XCD stream the same KV tiles in lockstep (L2 temporal locality).
// 4 waves, 16 q-rows/wave. Qb pre-scaled by 1/16. Kb [16384,512]. Vt [512,16384].
__global__ __launch_bounds__(256, 1) void flash_attn(
    const u16* __restrict__ Qb, const u16* __restrict__ Kb,
    const u16* __restrict__ Vt, float* __restrict__ out)
{
  __shared__ u16 Ks[2][32*512];    // K tile  [kv=32][d=512], 16B-slot XOR-swizzle (row&7)
  __shared__ u16 Vts[2][512*32];   // Vt tile [d=512][kv=32], slot swizzle (d^(d>>2))&3
  __shared__ u16 Plds[4][16*32];   // per-wave P, slot swizzle (q^(q>>2))&3
  const int tid = threadIdx.x;
  const int w = tid >> 6, l = tid & 63;
  const int lr = l & 15, lg = l >> 4;
  const int xcd = blockIdx.x & 7;
  const int idx = blockIdx.x >> 3;       // 0..31
  const int dir = xcd >> 2;
  const int qb  = (xcd & 3) * 32 + idx;  // 0..127
  const int qrow0 = dir*NSEQ + qb*64 + w*16;
  const int kvbase = (1-dir)*NSEQ;

  // Q fragments in registers: rows qrow0+lr, k = kt*32 + lg*8
  short8 qf[16];
  #pragma unroll
  for (int kt=0; kt<16; kt++)
    qf[kt] = *(const short8*)(Qb + (size_t)(qrow0 + lr)*OUTD + kt*32 + lg*8);

  f32x4 o[32];
  #pragma unroll
  for (int i=0;i<32;i++) o[i] = f32x4{0.f,0.f,0.f,0.f};
  float m[4]  = {-1e30f,-1e30f,-1e30f,-1e30f};
  float ls[4] = {0.f,0.f,0.f,0.f};

  u16* Pw = &Plds[w][0];
  const int fq = (lr ^ (lr>>2)) & 3;

  // stage K+Vt tile t into buffer buf (linear LDS dest, inverse-swizzled source)
  auto STAGE = [&](int buf, int t){
    u16* Kd = &Ks[buf][0];
    u16* Vd = &Vts[buf][0];
    #pragma unroll
    for (int i=0;i<8;i++){
      int sb = i*256 + w*64;
      int s = sb + l;
      int r = s >> 6;     // kv row 0..31
      int p = s & 63;     // 16B slot in row
      gload_lds16(Kb + (size_t)(kvbase + t*32 + r)*OUTD + ((p ^ (r&7))*8), Kd + sb*8);
    }
    #pragma unroll
    for (int i=0;i<8;i++){
      int sb = i*256 + w*64;
      int s = sb + l;
      int d = s >> 2;     // d row 0..511
      int p = s & 3;      // 16B slot in row
      int fd = (d ^ (d>>2)) & 3;
      gload_lds16(Vt + (size_t)d*MTOT + kvbase + t*32 + ((p ^ fd)*8), Vd + sb*8);
    }
  };

  STAGE(0, 0);
  __syncthreads();  // drain prologue stage

  const int NT = NSEQ/32;
  for (int t=0; t<NT; t++){
    const int cur = t & 1;
    // issue next tile's loads FIRST (overlap with compute below)
    if (t+1 < NT) STAGE(cur^1, t+1);

    const u16* Kc = &Ks[cur][0];
    const u16* Vc = &Vts[cur][0];

    // S = Q @ K^T  (A=Q rows, B=K rows; swizzled reads)
    f32x4 s0 = f32x4{0.f,0.f,0.f,0.f}, s1 = s0;
    __builtin_amdgcn_s_setprio(1);
    #pragma unroll
    for (int kt=0; kt<16; kt++){
      short8 b0 = *(const short8*)(Kc + (size_t)(lr)*512    + (((kt*4+lg) ^ (lr&7))*8));
      short8 b1 = *(const short8*)(Kc + (size_t)(16+lr)*512 + (((kt*4+lg) ^ (lr&7))*8));
      s0 = MFMA16(qf[kt], b0, s0);
      s1 = MFMA16(qf[kt], b1, s1);
    }
    __builtin_amdgcn_s_setprio(0);

    // online softmax with defer-max (THR=8): row = lg*4+j, cols across lr lanes
    float tm[4];
    #pragma unroll
    for (int j=0;j<4;j++){
      float mx = fmaxf(s0[j], s1[j]);
      mx = fmaxf(mx, __shfl_xor(mx, 1));
      mx = fmaxf(mx, __shfl_xor(mx, 2));
      mx = fmaxf(mx, __shfl_xor(mx, 4));
      mx = fmaxf(mx, __shfl_xor(mx, 8));
      tm[j] = mx;
    }
    bool need = (tm[0] > m[0]+8.f) || (tm[1] > m[1]+8.f) ||
                (tm[2] > m[2]+8.f) || (tm[3] > m[3]+8.f);
    if (__any(need)){
      float corr[4];
      #pragma unroll
      for (int j=0;j<4;j++){
        float mn = fmaxf(m[j], tm[j]);
        corr[j] = exp2f((m[j]-mn)*1.44269504f);
        m[j] = mn;
        ls[j] *= corr[j];
      }
      #pragma unroll
      for (int i=0;i<32;i++){
        o[i][0] *= corr[0]; o[i][1] *= corr[1]; o[i][2] *= corr[2]; o[i][3] *= corr[3];
      }
    }
    #pragma unroll
    for (int j=0;j<4;j++){
      float p0 = exp2f((s0[j]-m[j])*1.44269504f);
      float p1 = exp2f((s1[j]-m[j])*1.44269504f);
      s0[j] = p0; s1[j] = p1;
      float sm = p0 + p1;
      sm += __shfl_xor(sm, 1);
      sm += __shfl_xor(sm, 2);
      sm += __shfl_xor(sm, 4);
      sm += __shfl_xor(sm, 8);
      ls[j] += sm;
    }

    // P (C-layout) -> per-wave LDS as bf16 (A-layout source for PV)
    #pragma unroll
    for (int j=0;j<4;j++){
      int q = lg*4 + j;
      int fqw = (q ^ (q>>2)) & 3;
      int ps0 = (lr>>3) ^ fqw;            // col = lr
      int ps1 = ((16+lr)>>3) ^ fqw;       // col = 16+lr
      Pw[q*32 + ps0*8 + (lr&7)] = f2b(s0[j]);
      Pw[q*32 + ps1*8 + (lr&7)] = f2b(s1[j]);
    }

    // PV: O[16,512] += P[16,32] @ V[32,512]
    short8 pa = *(const short8*)(Pw + lr*32 + ((lg ^ fq)*8));
    __builtin_amdgcn_s_setprio(1);
    #pragma unroll
    for (int nj=0; nj<32; nj++){
      int d = nj*16 + lr;
      int fd = (d ^ (d>>2)) & 3;
      short8 bv = *(const short8*)(Vc + d*32 + ((lg ^ fd)*8));
      o[nj] = MFMA16(pa, bv, o[nj]);
    }
    __builtin_amdgcn_s_setprio(0);

    __syncthreads();  // one barrier/tile: next-tile loads drained, all waves done with cur
  }

  float inv[4];
  #pragma unroll
  for (int j=0;j<4;j++) inv[j] = 1.f / ls[j];
  #pragma unroll
  for (int nj=0; nj<32; nj++){
    int col = dir*OUTD + nj*16 + lr;
    #pragma unroll
    for (int j=0;j<4;j++){
      int row = qb*64 + w*16 + lg*4 + j;
      out[(size_t)row*(2*OUTD) + col] = o[nj][j]*inv[j];
    }
  }
}

// ---------------- workspace layout ----------------
#define OFF_W1T  ((size_t)0)                          // 1024*1024*2
#define OFF_W2T  (OFF_W1T + (size_t)1024*1024*2)      // 512*1024*2
#define OFF_WQT  (OFF_W2T + (size_t)512*1024*2)       // 512*512*2
#define OFF_WKT  (OFF_WQT + (size_t)512*512*2)
#define OFF_WVT  (OFF_WKT + (size_t)512*512*2)
#define OFF_XC   (OFF_WVT + (size_t)512*512*2)        // 16384*1024*2 (later: Qb,Kb)
#define OFF_H    (OFF_XC  + (size_t)MTOT*HIDDEN*2)    // 16384*1024*2 (later: Vt)
#define OFF_P    (OFF_H   + (size_t)MTOT*HIDDEN*2)    // 16384*512*2
#define OFF_QB   OFF_XC
#define OFF_KB   (OFF_XC + (size_t)MTOT*OUTD*2)
#define OFF_VT   OFF_H

extern "C" void kernel_launch(void* const* d_in, const int* in_sizes, int n_in,
                              void* d_out, int out_size, void* d_ws, size_t ws_size,
                              hipStream_t stream) {
  const float* za = (const float*)d_in[0];
  const float* zb = (const float*)d_in[1];
  const float* W1 = (const float*)d_in[2];
  const float* b1 = (const float*)d_in[3];
  const float* W2 = (const float*)d_in[4];
  const float* b2 = (const float*)d_in[5];
  const float* Wq = (const float*)d_in[6];
  const float* bq = (const float*)d_in[7];
  const float* Wk = (const float*)d_in[8];
  const float* bk = (const float*)d_in[9];
  const float* Wv = (const float*)d_in[10];
  const float* bv = (const float*)d_in[11];
  float* out = (float*)d_out;
  char* ws = (char*)d_ws;

  u16* W1T = (u16*)(ws + OFF_W1T);
  u16* W2T = (u16*)(ws + OFF_W2T);
  u16* WqT = (u16*)(ws + OFF_WQT);
  u16* WkT = (u16*)(ws + OFF_WKT);
  u16* WvT = (u16*)(ws + OFF_WVT);
  u16* Xc  = (u16*)(ws + OFF_XC);
  u16* H   = (u16*)(ws + OFF_H);
  u16* P   = (u16*)(ws + OFF_P);
  u16* Qb  = (u16*)(ws + OFF_QB);
  u16* Kb  = (u16*)(ws + OFF_KB);
  u16* Vt  = (u16*)(ws + OFF_VT);

  // inputs -> bf16 (za | zb stacked)
  cvt_bf16_kernel<<<2048, 256, 0, stream>>>(za, Xc, NSEQ*HIDDEN/4);
  cvt_bf16_kernel<<<2048, 256, 0, stream>>>(zb, Xc + (size_t)NSEQ*HIDDEN, NSEQ*HIDDEN/4);
  // weight transposes (f32 -> bf16)
  transpose_bf16_kernel<<<dim3(32,32), dim3(32,8), 0, stream>>>(W1, W1T, 1024, 1024);
  transpose_bf16_kernel<<<dim3(16,32), dim3(32,8), 0, stream>>>(W2, W2T, 1024, 512);
  transpose_bf16_kernel<<<dim3(16,16), dim3(32,8), 0, stream>>>(Wq, WqT, 512, 512);
  transpose_bf16_kernel<<<dim3(16,16), dim3(32,8), 0, stream>>>(Wk, WkT, 512, 512);
  transpose_bf16_kernel<<<dim3(16,16), dim3(32,8), 0, stream>>>(Wv, WvT, 512, 512);

  // H = ELU(Xc @ W1 + b1)    [16384,1024]
  gemm_bt<true,false><<<dim3(HIDDEN/128, MTOT/128), 256, 0, stream>>>(
      Xc, W1T, b1, H, MTOT, HIDDEN, HIDDEN, 1.f);
  // P = H @ W2 + b2          [16384,512]
  gemm_bt<false,false><<<dim3(OUTD/128, MTOT/128), 256, 0, stream>>>(
      H, W2T, b2, P, MTOT, OUTD, HIDDEN, 1.f);
  // Qb = (P @ Wq + bq)/16    [16384,512]   (scale folded in)
  gemm_bt<false,false><<<dim3(OUTD/128, MTOT/128), 256, 0, stream>>>(
      P, WqT, bq, Qb, MTOT, OUTD, OUTD, 0.0625f);
  // Kb = P @ Wk + bk         [16384,512]
  gemm_bt<false,false><<<dim3(OUTD/128, MTOT/128), 256, 0, stream>>>(
      P, WkT, bk, Kb, MTOT, OUTD, OUTD, 1.f);
  // Vt = (P @ Wv + bv)^T as GEMM: Vt[d,j] = sum_k WvT[d,k]*P[j,k] + bv[d]   [512,16384]
  gemm_bt<false,true><<<dim3(MTOT/128, OUTD/128), 256, 0, stream>>>(
      WvT, P, bv, Vt, OUTD, MTOT, OUTD, 1.f);

  // flash attention, both directions
  flash_attn<<<256, 256, 0, stream>>>(Qb, Kb, Vt, out);
}

// Round 5
// 704.180 us; speedup vs baseline: 1.7353x; 1.6328x over previous
//
#include <hip/hip_runtime.h>
#include <hip/hip_bf16.h>
#include <stdint.h>

#define HIDDEN 1024
#define OUTD   512
#define NSEQ   8192
#define MTOT   16384  // 2*NSEQ

typedef unsigned short u16;
typedef __attribute__((ext_vector_type(8))) short short8;  // 8 bf16 (4 VGPRs)
typedef __attribute__((ext_vector_type(4))) float f32x4;

__device__ __forceinline__ u16 f2b(float f){
  union { __hip_bfloat16 h; u16 u; } c; c.h = __float2bfloat16(f); return c.u;
}

__device__ __forceinline__ void gload_lds16(const void* g, void* l){
  __builtin_amdgcn_global_load_lds(
    (const __attribute__((address_space(1))) uint32_t*)(uintptr_t)g,
    (__attribute__((address_space(3))) uint32_t*)(uintptr_t)l, 16, 0, 0);
}

#define MFMA16(a,b,c) __builtin_amdgcn_mfma_f32_16x16x32_bf16((a),(b),(c),0,0,0)

// ---------------- f32 -> bf16 convert ----------------
__global__ void cvt_bf16_kernel(const float* __restrict__ in, u16* __restrict__ out, int n4){
  int i = blockIdx.x*blockDim.x + threadIdx.x;
  int stride = gridDim.x*blockDim.x;
  for (; i < n4; i += stride){
    float4 v = ((const float4*)in)[i];
    ushort4 o;
    o.x = f2b(v.x); o.y = f2b(v.y); o.z = f2b(v.z); o.w = f2b(v.w);
    ((ushort4*)out)[i] = o;
  }
}

// ---------------- transpose f32[R][C] -> bf16[C][R] ----------------
__global__ void transpose_bf16_kernel(const float* __restrict__ in, u16* __restrict__ out, int R, int C){
  __shared__ float t[32][33];
  int tx = threadIdx.x, ty = threadIdx.y;
  int c0 = blockIdx.x*32, r0 = blockIdx.y*32;
  #pragma unroll
  for (int i = ty; i < 32; i += 8) t[i][tx] = in[(size_t)(r0+i)*C + c0 + tx];
  __syncthreads();
  #pragma unroll
  for (int i = ty; i < 32; i += 8) out[(size_t)(c0+i)*R + r0 + tx] = f2b(t[tx][i]);
}

// ---------------- GEMM: C[M,N] = A[M,K] @ BT[N,K]^T (+bias, opt ELU, *scale), bf16 out ----
template<bool ELU_ACT, bool BIAS_ROW>
__global__ __launch_bounds__(256, 2) void gemm_bt(
    const u16* __restrict__ A, const u16* __restrict__ BT,
    const float* __restrict__ bias, u16* __restrict__ C,
    int M, int N, int K, float outscale)
{
  __shared__ u16 As[128*32];
  __shared__ u16 Bs[128*32];
  const int tid = threadIdx.x;
  const int w = tid >> 6, l = tid & 63;
  const int lr = l & 15, lg = l >> 4;
  const int brow = blockIdx.y * 128, bcol = blockIdx.x * 128;
  const int wr = w >> 1, wc = w & 1;
  f32x4 acc[4][4];
  #pragma unroll
  for (int i=0;i<4;i++)
    #pragma unroll
    for (int j=0;j<4;j++) acc[i][j] = f32x4{0.f,0.f,0.f,0.f};

  for (int k0 = 0; k0 < K; k0 += 32){
    __syncthreads();
    {
      int sb = w*64;
      int s0 = sb + l;
      int s1 = 256 + sb + l;
      gload_lds16(A  + (size_t)(brow + (s0>>2))*K + k0 + (s0&3)*8, As + sb*8);
      gload_lds16(A  + (size_t)(brow + (s1>>2))*K + k0 + (s1&3)*8, As + (256+sb)*8);
      gload_lds16(BT + (size_t)(bcol + (s0>>2))*K + k0 + (s0&3)*8, Bs + sb*8);
      gload_lds16(BT + (size_t)(bcol + (s1>>2))*K + k0 + (s1&3)*8, Bs + (256+sb)*8);
    }
    __syncthreads();
    short8 a[4], b[4];
    #pragma unroll
    for (int i=0;i<4;i++){
      a[i] = *(const short8*)(As + (wr*64 + i*16 + lr)*32 + lg*8);
      b[i] = *(const short8*)(Bs + (wc*64 + i*16 + lr)*32 + lg*8);
    }
    #pragma unroll
    for (int i=0;i<4;i++)
      #pragma unroll
      for (int j=0;j<4;j++)
        acc[i][j] = MFMA16(a[i], b[j], acc[i][j]);
  }

  // C/D layout (m89-verified): col = lane&15, row = (lane>>4)*4 + reg
  #pragma unroll
  for (int i=0;i<4;i++)
    #pragma unroll
    for (int j=0;j<4;j++){
      int col = bcol + wc*64 + j*16 + lr;
      float bc = BIAS_ROW ? 0.f : bias[col];
      #pragma unroll
      for (int r=0;r<4;r++){
        int row = brow + wr*64 + i*16 + lg*4 + r;
        float v = acc[i][j][r] + (BIAS_ROW ? bias[row] : bc);
        if (ELU_ACT) v = v > 0.f ? v : expm1f(v);
        v *= outscale;
        C[(size_t)row*N + col] = f2b(v);
      }
    }
}

// ---------------- flash attention v3 ----------------
// 512 threads (8 waves), 16 q-rows/wave -> 128 q-rows/block.
// KV-split x2: grid = 256 = {dir x half x 64 q-blocks}. Each block does 4096 kv
// (128 tiles of 32) and writes unnormalized partials (O~, m, l); merge_kernel combines.
// Swapped QK^T: S = mfma(K_A, Q_B) -> lane holds full P-row for q = lane&15.
// Softmax: 7 in-lane ops + 2 shuffles. PV = mfma(V_A, P_B): O[d][q], q = lane&15.
__global__ __launch_bounds__(512, 2) void flash_attn(
    const u16* __restrict__ Qb, const u16* __restrict__ Kb,
    const u16* __restrict__ Vt, float* __restrict__ Opart,
    float2* __restrict__ MLpart)
{
  __shared__ u16 Ks[2][32*512];    // K tile  [kv=32][d=512], 16B-slot XOR-swizzle (row&7)
  __shared__ u16 Vts[2][512*32];   // Vt tile [d=512][kv=32], slot swizzle (d^(d>>2))&3
  __shared__ u16 Plds[8][16*32];   // per-wave P [q=16][kv=32], 16B-pair swizzle (q&3)
  const int tid = threadIdx.x;
  const int w = tid >> 6, l = tid & 63;
  const int lr = l & 15, lg = l >> 4;
  // XCD-aware: xcd = bx&7; combo (dir,half) per XCD-pair; 64 CUs share one KV stream
  const int xcd = blockIdx.x & 7;
  const int idx = blockIdx.x >> 3;          // 0..31
  const int dir = xcd >> 2;                 // 0..1
  const int half = (xcd >> 1) & 1;          // 0..1
  const int qb  = (xcd & 1)*32 + idx;       // 0..63
  const int qrow0 = dir*NSEQ + qb*128 + w*16;
  const int kv0 = (1-dir)*NSEQ + half*(NSEQ/2);
  const int NT = (NSEQ/2)/32;               // 128 tiles

  // Q fragments (B-operand): col=q=lr, k = kt*32 + lg*8
  short8 qf[16];
  #pragma unroll
  for (int kt=0; kt<16; kt++)
    qf[kt] = *(const short8*)(Qb + (size_t)(qrow0 + lr)*OUTD + kt*32 + lg*8);

  f32x4 o[32];                              // O[d][q=lr]: d = nj*16 + lg*4 + r
  #pragma unroll
  for (int i=0;i<32;i++) o[i] = f32x4{0.f,0.f,0.f,0.f};
  float m = -1e30f, ls = 0.f;               // per-lane scalars (q = lr)

  u16* Pw = &Plds[w][0];

  // stage K+Vt tile t into buffer buf (linear LDS dest, inverse-swizzled source)
  auto STAGE = [&](int buf, int t){
    u16* Kd = &Ks[buf][0];
    u16* Vd = &Vts[buf][0];
    #pragma unroll
    for (int i=0;i<4;i++){
      int g = w*4 + i;                      // kv row 0..31, one 1KB row per op
      gload_lds16(Kb + (size_t)(kv0 + t*32 + g)*OUTD + ((l ^ (g&7))*8), Kd + g*512);
    }
    #pragma unroll
    for (int i=0;i<4;i++){
      int g = w*4 + i;
      int d = g*16 + (l>>2);                // d row 0..511
      int p = l & 3;                        // 16B slot in row
      int fd = (d ^ (d>>2)) & 3;
      gload_lds16(Vt + (size_t)d*MTOT + kv0 + t*32 + ((p ^ fd)*8), Vd + (g*64 + l)*8);
    }
  };

  STAGE(0, 0);
  __syncthreads();

  for (int t=0; t<NT; t++){
    const int cur = t & 1;
    if (t+1 < NT) STAGE(cur^1, t+1);       // overlap with compute below

    const u16* Kc = &Ks[cur][0];
    const u16* Vc = &Vts[cur][0];

    // S = mfma(K_A, Q_B): s0 rows kv 0..15, s1 rows kv 16..31; col = q = lr
    f32x4 s0 = f32x4{0.f,0.f,0.f,0.f}, s1 = s0;
    __builtin_amdgcn_s_setprio(1);
    #pragma unroll
    for (int kt=0; kt<16; kt++){
      short8 ka = *(const short8*)(Kc + (size_t)(lr)*512    + (((kt*4+lg) ^ (lr&7))*8));
      short8 kb = *(const short8*)(Kc + (size_t)(16+lr)*512 + (((kt*4+lg) ^ (lr&7))*8));
      s0 = MFMA16(ka, qf[kt], s0);
      s1 = MFMA16(kb, qf[kt], s1);
    }
    __builtin_amdgcn_s_setprio(0);

    // per-lane online softmax for q=lr over kv = lg*4+r (s0), 16+lg*4+r (s1)
    float mx = fmaxf(fmaxf(fmaxf(s0[0],s0[1]), fmaxf(s0[2],s0[3])),
                     fmaxf(fmaxf(s1[0],s1[1]), fmaxf(s1[2],s1[3])));
    mx = fmaxf(mx, __shfl_xor(mx, 16));
    mx = fmaxf(mx, __shfl_xor(mx, 32));
    bool need = mx > m + 8.f;               // defer-max THR=8
    if (__any(need)){
      float mn = fmaxf(m, mx);
      float corr = exp2f((m - mn)*1.44269504f);
      m = mn; ls *= corr;
      #pragma unroll
      for (int i=0;i<32;i++){
        o[i][0] *= corr; o[i][1] *= corr; o[i][2] *= corr; o[i][3] *= corr;
      }
    }
    float p0[4], p1[4], sm = 0.f;
    #pragma unroll
    for (int r=0;r<4;r++){
      p0[r] = exp2f((s0[r]-m)*1.44269504f);
      p1[r] = exp2f((s1[r]-m)*1.44269504f);
      sm += p0[r] + p1[r];
    }
    sm += __shfl_xor(sm, 16);
    sm += __shfl_xor(sm, 32);
    ls += sm;

    // P -> per-wave LDS (bf16), two ds_write_b64, pair-swizzle p' = p ^ (q&3)
    ushort4 w0, w1;
    w0.x = f2b(p0[0]); w0.y = f2b(p0[1]); w0.z = f2b(p0[2]); w0.w = f2b(p0[3]);
    w1.x = f2b(p1[0]); w1.y = f2b(p1[1]); w1.z = f2b(p1[2]); w1.w = f2b(p1[3]);
    *(ushort4*)(Pw + lr*32 + (((lg>>1) ^ (lr&3))*8)     + (lg&1)*4) = w0;
    *(ushort4*)(Pw + lr*32 + (((2+(lg>>1)) ^ (lr&3))*8) + (lg&1)*4) = w1;

    // PV: O[d][q] += mfma(V_A rows=d, P_B col=q); P read: kv-pair lg, swizzled
    short8 pb = *(const short8*)(Pw + lr*32 + ((lg ^ (lr&3))*8));
    __builtin_amdgcn_s_setprio(1);
    #pragma unroll
    for (int nj=0; nj<32; nj++){
      int d = nj*16 + lr;
      int fd = (d ^ (d>>2)) & 3;
      short8 va = *(const short8*)(Vc + d*32 + ((lg ^ fd)*8));
      o[nj] = MFMA16(va, pb, o[nj]);
    }
    __builtin_amdgcn_s_setprio(0);

    __syncthreads();  // all waves done with cur; next-tile loads drained
  }

  // write unnormalized partials: O~, (m, ls)
  const int qg = dir*NSEQ + qb*128 + w*16 + lr;           // 0..16383
  float* Od = Opart + ((size_t)half*MTOT + qg)*OUTD;
  #pragma unroll
  for (int nj=0; nj<32; nj++)
    *(f32x4*)(Od + nj*16 + lg*4) = o[nj];
  if (lg == 0)
    MLpart[half*MTOT + qg] = make_float2(m, ls);
}

// ---------------- merge the two KV-half partials ----------------
__global__ void merge_kernel(const float* __restrict__ Opart,
                             const float2* __restrict__ MLpart,
                             float* __restrict__ out){
  int i = blockIdx.x*blockDim.x + threadIdx.x;   // over MTOT*128 float4s
  int qg = i >> 7, d4 = i & 127;
  float2 ml0 = MLpart[qg], ml1 = MLpart[MTOT + qg];
  float M = fmaxf(ml0.x, ml1.x);
  float w0 = exp2f((ml0.x - M)*1.44269504f);
  float w1 = exp2f((ml1.x - M)*1.44269504f);
  float inv = 1.f / (ml0.y*w0 + ml1.y*w1);
  f32x4 a = ((const f32x4*)Opart)[(size_t)qg*128 + d4];
  f32x4 b = ((const f32x4*)Opart)[(size_t)MTOT*128 + (size_t)qg*128 + d4];
  f32x4 r;
  #pragma unroll
  for (int j=0;j<4;j++) r[j] = (a[j]*w0 + b[j]*w1)*inv;
  int row = qg & (NSEQ-1), dir = qg >> 13;
  ((f32x4*)out)[(size_t)row*256 + dir*128 + d4] = r;
}

// ---------------- workspace layout ----------------
#define OFF_W1T  ((size_t)0)                          // 1024*1024*2
#define OFF_W2T  (OFF_W1T + (size_t)1024*1024*2)      // 512*1024*2
#define OFF_WQT  (OFF_W2T + (size_t)512*1024*2)       // 512*512*2
#define OFF_WKT  (OFF_WQT + (size_t)512*512*2)
#define OFF_WVT  (OFF_WKT + (size_t)512*512*2)
#define OFF_XC   (OFF_WVT + (size_t)512*512*2)        // 16384*1024*2 (later: Qb,Kb)
#define OFF_H    (OFF_XC  + (size_t)MTOT*HIDDEN*2)    // 16384*1024*2 (later: Vt)
#define OFF_P    (OFF_H   + (size_t)MTOT*HIDDEN*2)    // 16384*512*2
#define OFF_QB   OFF_XC
#define OFF_KB   (OFF_XC + (size_t)MTOT*OUTD*2)
#define OFF_VT   OFF_H
#define OFF_ML   (OFF_P  + (size_t)MTOT*OUTD*2)       // 2*16384*float2
#define OFF_OP   (OFF_ML + (size_t)2*MTOT*8)          // 2*16384*512*f32 = 64MB

extern "C" void kernel_launch(void* const* d_in, const int* in_sizes, int n_in,
                              void* d_out, int out_size, void* d_ws, size_t ws_size,
                              hipStream_t stream) {
  const float* za = (const float*)d_in[0];
  const float* zb = (const float*)d_in[1];
  const float* W1 = (const float*)d_in[2];
  const float* b1 = (const float*)d_in[3];
  const float* W2 = (const float*)d_in[4];
  const float* b2 = (const float*)d_in[5];
  const float* Wq = (const float*)d_in[6];
  const float* bq = (const float*)d_in[7];
  const float* Wk = (const float*)d_in[8];
  const float* bk = (const float*)d_in[9];
  const float* Wv = (const float*)d_in[10];
  const float* bv = (const float*)d_in[11];
  float* out = (float*)d_out;
  char* ws = (char*)d_ws;

  u16* W1T = (u16*)(ws + OFF_W1T);
  u16* W2T = (u16*)(ws + OFF_W2T);
  u16* WqT = (u16*)(ws + OFF_WQT);
  u16* WkT = (u16*)(ws + OFF_WKT);
  u16* WvT = (u16*)(ws + OFF_WVT);
  u16* Xc  = (u16*)(ws + OFF_XC);
  u16* H   = (u16*)(ws + OFF_H);
  u16* P   = (u16*)(ws + OFF_P);
  u16* Qb  = (u16*)(ws + OFF_QB);
  u16* Kb  = (u16*)(ws + OFF_KB);
  u16* Vt  = (u16*)(ws + OFF_VT);
  float2* ML = (float2*)(ws + OFF_ML);
  float*  OP = (float*)(ws + OFF_OP);

  // inputs -> bf16 (za | zb stacked)
  cvt_bf16_kernel<<<2048, 256, 0, stream>>>(za, Xc, NSEQ*HIDDEN/4);
  cvt_bf16_kernel<<<2048, 256, 0, stream>>>(zb, Xc + (size_t)NSEQ*HIDDEN, NSEQ*HIDDEN/4);
  // weight transposes (f32 -> bf16)
  transpose_bf16_kernel<<<dim3(32,32), dim3(32,8), 0, stream>>>(W1, W1T, 1024, 1024);
  transpose_bf16_kernel<<<dim3(16,32), dim3(32,8), 0, stream>>>(W2, W2T, 1024, 512);
  transpose_bf16_kernel<<<dim3(16,16), dim3(32,8), 0, stream>>>(Wq, WqT, 512, 512);
  transpose_bf16_kernel<<<dim3(16,16), dim3(32,8), 0, stream>>>(Wk, WkT, 512, 512);
  transpose_bf16_kernel<<<dim3(16,16), dim3(32,8), 0, stream>>>(Wv, WvT, 512, 512);

  // H = ELU(Xc @ W1 + b1)    [16384,1024]
  gemm_bt<true,false><<<dim3(HIDDEN/128, MTOT/128), 256, 0, stream>>>(
      Xc, W1T, b1, H, MTOT, HIDDEN, HIDDEN, 1.f);
  // P = H @ W2 + b2          [16384,512]
  gemm_bt<false,false><<<dim3(OUTD/128, MTOT/128), 256, 0, stream>>>(
      H, W2T, b2, P, MTOT, OUTD, HIDDEN, 1.f);
  // Qb = (P @ Wq + bq)/16    [16384,512]   (scale folded in)
  gemm_bt<false,false><<<dim3(OUTD/128, MTOT/128), 256, 0, stream>>>(
      P, WqT, bq, Qb, MTOT, OUTD, OUTD, 0.0625f);
  // Kb = P @ Wk + bk         [16384,512]
  gemm_bt<false,false><<<dim3(OUTD/128, MTOT/128), 256, 0, stream>>>(
      P, WkT, bk, Kb, MTOT, OUTD, OUTD, 1.f);
  // Vt = (P @ Wv + bv)^T as GEMM: Vt[d,j] = sum_k WvT[d,k]*P[j,k] + bv[d]   [512,16384]
  gemm_bt<false,true><<<dim3(MTOT/128, OUTD/128), 256, 0, stream>>>(
      WvT, P, bv, Vt, OUTD, MTOT, OUTD, 1.f);

  // flash attention (partials), then merge
  flash_attn<<<256, 512, 0, stream>>>(Qb, Kb, Vt, OP, ML);
  merge_kernel<<<(MTOT*128)/256, 256, 0, stream>>>(OP, ML, out);
}